// Round 11
// baseline (109.327 us; speedup 1.0000x reference)
//
#include <hip/hip_runtime.h>
#include <hip/hip_bf16.h>
#include <stdint.h>

// Problem constants (fixed by the reference)
#define NQ    32768
#define NKV   32768
#define CDIM  256
#define NHEADS 8
#define NPTS  4
#define NHALF (NQ / 2)

using bf16x8 = __attribute__((ext_vector_type(8))) short;
using f32x4  = __attribute__((ext_vector_type(4))) float;
using u16x8  = __attribute__((ext_vector_type(8))) ushort;

static __device__ __forceinline__ ushort f2bf(float f) {
  uint32_t u = __float_as_uint(f);
  return (ushort)((u + 0x7FFFu + ((u >> 16) & 1u)) >> 16);  // RNE
}
static __device__ __forceinline__ float bf2f(ushort h) {
  return __uint_as_float(((uint32_t)h) << 16);
}
static __device__ __forceinline__ void async16(const void* g, void* l) {
  __builtin_amdgcn_global_load_lds(
      (const __attribute__((address_space(1))) uint32_t*)g,
      (__attribute__((address_space(3))) uint32_t*)l, 16, 0, 0);
}
#define WAIT_VM(N) do { asm volatile("s_waitcnt vmcnt(" #N ")" ::: "memory"); \
                        __builtin_amdgcn_sched_barrier(0); } while (0)

// ---------------------------------------------------------------------------
// K0: both W transposes in one launch. b<256: Wv -> WvT, else Wout -> WoT.
__global__ __launch_bounds__(256) void transpose_both(
    const float* __restrict__ Wv, const float* __restrict__ Wout,
    ushort* __restrict__ WvT, ushort* __restrict__ WoT) {
  int b = blockIdx.x, k = threadIdx.x;
  if (b < 256) WvT[b * 256 + k] = f2bf(Wv[k * 256 + b]);
  else { int j = b - 256; WoT[j * 256 + k] = f2bf(Wout[k * 256 + j]); }
}

// ---------------------------------------------------------------------------
// GEMM body: C[M,256] = A[M,256] * B + bias (A bf16, BT = B^T bf16, C f32).
// 128x128 tile, BK=32, 4 waves 2x2, 16KB LDS.
static __device__ __forceinline__ void gemm_body(
    const ushort* __restrict__ A, const ushort* __restrict__ BT,
    const float* __restrict__ bias, float* __restrict__ Cf,
    char* smem, int bid, int moff) {
  ushort* Alds = (ushort*)smem;
  ushort* Blds = (ushort*)smem + 128 * 32;
  const int t = threadIdx.x;
  const int wave = t >> 6, lane = t & 63;
  const int mt = bid >> 1, nt = bid & 1;
  const int m0 = moff + mt * 128, n0 = nt * 128;
  const int wr = wave >> 1, wc = wave & 1;
  const int r16 = lane & 15, kb = (lane >> 4) * 8;

  f32x4 acc[4][4] = {};

  for (int kt = 0; kt < 256; kt += 32) {
    __syncthreads();
#pragma unroll
    for (int it = 0; it < 2; ++it) {
      int c = it * 256 + t;
      int row = c >> 2, cc = c & 3;
      async16(A  + ((size_t)(m0 + row) * 256 + kt + cc * 8),
              Alds + (size_t)(it * 256 + wave * 64) * 8);
      async16(BT + ((size_t)((nt * 128) + row) * 256 + kt + cc * 8),
              Blds + (size_t)(it * 256 + wave * 64) * 8);
    }
    __syncthreads();

    bf16x8 af[4], bfr[4];
#pragma unroll
    for (int m = 0; m < 4; ++m)
      af[m] = *(const bf16x8*)&Alds[(wr * 64 + m * 16 + r16) * 32 + kb];
#pragma unroll
    for (int n = 0; n < 4; ++n)
      bfr[n] = *(const bf16x8*)&Blds[(wc * 64 + n * 16 + r16) * 32 + kb];
#pragma unroll
    for (int m = 0; m < 4; ++m)
#pragma unroll
      for (int n = 0; n < 4; ++n)
        acc[m][n] = __builtin_amdgcn_mfma_f32_16x16x32_bf16(af[m], bfr[n],
                                                            acc[m][n], 0, 0, 0);
  }

  const int rg = lane >> 4;
#pragma unroll
  for (int m = 0; m < 4; ++m)
#pragma unroll
    for (int n = 0; n < 4; ++n) {
      int gc = n0 + wc * 64 + n * 16 + r16;
      float bb = bias[gc];
#pragma unroll
      for (int r = 0; r < 4; ++r) {
        int gr = m0 + wr * 64 + m * 16 + rg * 4 + r;
        Cf[(size_t)gr * 256 + gc] = acc[m][n][r] + bb;
      }
    }
}

// ---------------------------------------------------------------------------
// fa body: value GEMM, A f32 (bf16-converted during staging), C transposed
// to vtabT[H][M][Ch] through a 16KB LDS transpose epilogue (coalesced u16x8).
static __device__ __forceinline__ void fa_body(
    const float* __restrict__ Af, const ushort* __restrict__ BT,
    const float* __restrict__ bias, ushort* __restrict__ CbT,
    char* smem, int bid) {
  ushort* S = (ushort*)smem;              // 16KB: A half + B half; epilogue reuse
  ushort* Alds = S;
  ushort* Blds = S + 128 * 32;
  const int t = threadIdx.x;
  const int wave = t >> 6, lane = t & 63;
  const int mt = bid >> 1, nt = bid & 1;
  const int m0 = mt * 128, n0 = nt * 128;
  const int wr = wave >> 1, wc = wave & 1;
  const int r16 = lane & 15, kb = (lane >> 4) * 8;

  f32x4 acc[4][4] = {};

  for (int kt = 0; kt < 256; kt += 32) {
    __syncthreads();
#pragma unroll
    for (int it = 0; it < 2; ++it) {  // B via global_load_lds (bf16 already)
      int c = it * 256 + t;
      int row = c >> 2, cc = c & 3;
      async16(BT + ((size_t)(n0 + row) * 256 + kt + cc * 8),
              Blds + (size_t)(it * 256 + wave * 64) * 8);
    }
#pragma unroll
    for (int it = 0; it < 2; ++it) {  // A: f32 -> reg -> bf16 -> ds_write
      int c = it * 256 + t;
      int row = c >> 2, cc = c & 3;
      const float* src = Af + (size_t)(m0 + row) * 256 + kt + cc * 8;
      f32x4 a = *(const f32x4*)src;
      f32x4 b = *(const f32x4*)(src + 4);
      u16x8 w;
#pragma unroll
      for (int e = 0; e < 4; ++e) { w[e] = f2bf(a[e]); w[4 + e] = f2bf(b[e]); }
      *(u16x8*)&Alds[(size_t)c * 8] = w;   // c*8 == row*32 + cc*8
    }
    __syncthreads();  // covers vmcnt (B) + lgkm (A ds_write)

    bf16x8 af[4], bfr[4];
#pragma unroll
    for (int m = 0; m < 4; ++m)
      af[m] = *(const bf16x8*)&Alds[(wr * 64 + m * 16 + r16) * 32 + kb];
#pragma unroll
    for (int n = 0; n < 4; ++n)
      bfr[n] = *(const bf16x8*)&Blds[(wc * 64 + n * 16 + r16) * 32 + kb];
#pragma unroll
    for (int m = 0; m < 4; ++m)
#pragma unroll
      for (int n = 0; n < 4; ++n)
        acc[m][n] = __builtin_amdgcn_mfma_f32_16x16x32_bf16(af[m], bfr[n],
                                                            acc[m][n], 0, 0, 0);
  }

  // epilogue: LDS transpose -> coalesced vtabT stores (2 passes)
  const int rg = lane >> 4;
  const int h0 = n0 >> 5;
#pragma unroll
  for (int pass = 0; pass < 2; ++pass) {
    __syncthreads();
    if (wc == pass) {
#pragma unroll
      for (int m = 0; m < 4; ++m)
#pragma unroll
        for (int nn = 0; nn < 4; ++nn) {
          int col = nn * 16 + r16;
          int hh = col >> 5, ch = col & 31;
          float bb = bias[n0 + wc * 64 + col];
#pragma unroll
          for (int r = 0; r < 4; ++r) {
            int row = wr * 64 + m * 16 + rg * 4 + r;
            S[(hh * 128 + row) * 32 + ch] = f2bf(acc[m][nn][r] + bb);
          }
        }
    }
    __syncthreads();
#pragma unroll
    for (int i = 0; i < 4; ++i) {
      int chunk = i * 256 + t;
      int hh = chunk >> 9;
      int within = chunk & 511;
      u16x8 w = *(const u16x8*)&S[chunk * 8];
      ushort* dst = CbT + ((size_t)(h0 + pass * 2 + hh) * NKV + m0) * 32;
      *(u16x8*)(dst + within * 8) = w;
    }
  }
}

// ---------------------------------------------------------------------------
// loc body: loc_raw[N,64] = query @ [Wr_even | Wo_even]  (fp32, 33KB LDS).
static __device__ __forceinline__ void loc_body(
    const float* __restrict__ Q, const float* __restrict__ Wr,
    const float* __restrict__ Wo, float* __restrict__ locr,
    char* smem, int bid) {
  float (*AT)[68] = (float(*)[68])smem;                  // [64][68]
  float (*Bl)[64] = (float(*)[64])(smem + 64 * 68 * 4);  // [64][64]
  const int m0 = bid * 64;
  const int t = threadIdx.x;
  const int tr = t >> 4, tc = t & 15;
  float acc[4][4] = {};

  for (int k0 = 0; k0 < 256; k0 += 64) {
    __syncthreads();
#pragma unroll
    for (int i = 0; i < 4; ++i) {
      int row = (t >> 4) + 16 * i;
      int kk = (t & 15) * 4;
      float4 v = *(const float4*)&Q[(size_t)(m0 + row) * 256 + k0 + kk];
      AT[kk + 0][row] = v.x; AT[kk + 1][row] = v.y;
      AT[kk + 2][row] = v.z; AT[kk + 3][row] = v.w;
    }
#pragma unroll
    for (int i = 0; i < 16; ++i) {
      int j = t & 63;
      int kk = (t >> 6) + 4 * i;
      float v = (j < 32) ? Wr[(size_t)(k0 + kk) * 64 + 2 * j]
                         : Wo[(size_t)(k0 + kk) * 64 + 2 * (j - 32)];
      Bl[kk][j] = v;
    }
    __syncthreads();
#pragma unroll 8
    for (int kk = 0; kk < 64; ++kk) {
      float4 a = *(const float4*)&AT[kk][tr * 4];
      float4 b = *(const float4*)&Bl[kk][tc * 4];
      float av[4] = {a.x, a.y, a.z, a.w};
      float bv4[4] = {b.x, b.y, b.z, b.w};
#pragma unroll
      for (int i = 0; i < 4; ++i)
#pragma unroll
        for (int jj = 0; jj < 4; ++jj) acc[i][jj] += av[i] * bv4[jj];
    }
  }
#pragma unroll
  for (int i = 0; i < 4; ++i)
#pragma unroll
    for (int jj = 0; jj < 4; ++jj)
      locr[(size_t)(m0 + tr * 4 + i) * 64 + tc * 4 + jj] = acc[i][jj];
}

// ---------------------------------------------------------------------------
// attn body (r8 structure — at its measured structural floor).
// Wave = 1 query row; v pairs staged to LDS (4KB/wave, vtabT layout),
// k/q per-lane register loads. 16KB LDS per block.
static __device__ __forceinline__ void attn_body(
    const float* __restrict__ query, const float* __restrict__ key,
    const ushort* __restrict__ vtabT, const float* __restrict__ locr,
    const float* __restrict__ br, const float* __restrict__ bo,
    ushort* __restrict__ out2, char* smem, int bid, int n0q) {
  const int wave = threadIdx.x >> 6, l = threadIdx.x & 63;
  const int j = l & 31;
  const int n = n0q + bid * 4 + wave;
  const int Mm1 = NKV - 1;
  char* vbuf = smem + wave * 4096;

  float rr = locr[(size_t)n * 64 + j];
  float oo = locr[(size_t)n * 64 + 32 + j];
  float ref = 1.0f / (1.0f + expf(-(rr + br[2 * j])));
  float x = (ref + (oo + bo[2 * j])) * (float)Mm1;
  float xf = floorf(x);
  int x0 = (int)fminf(fmaxf(xf, 0.0f), (float)Mm1);
  int x1 = (x0 + 1 > Mm1) ? Mm1 : x0 + 1;
  float wx = x - (float)x0;
  float w0 = 1.0f - wx;

  // stage v pairs FIRST (latency hides under score phase)
  {
    const int pg3 = l >> 3, c7 = l & 7;
    const int sc = c7 ^ pg3;
#pragma unroll
    for (int i = 0; i < 4; ++i) {
      int pg = i * 8 + pg3;
      int row = __shfl(x0, pg, 64);
      async16(vtabT + ((size_t)(pg >> 2) * NKV + row) * 32 + sc * 8,
              vbuf + i * 1024);
    }
  }
  __builtin_amdgcn_sched_barrier(0);

  // k + q per-lane register loads (lane-local rows, no shuffles)
  const int myrow = (l < 32) ? x0 : x1;
  const float* kr = key + (size_t)myrow * 256 + (j >> 2) * 32;
  const float* qr = query + (size_t)n * 256 + (j >> 2) * 32;
  f32x4 kv[8], qv[8];
#pragma unroll
  for (int c = 0; c < 8; ++c) kv[c] = *(const f32x4*)(kr + c * 4);
#pragma unroll
  for (int c = 0; c < 8; ++c) qv[c] = *(const f32x4*)(qr + c * 4);
  __builtin_amdgcn_sched_barrier(0);

  float dot = 0.f;
#pragma unroll
  for (int c = 0; c < 8; ++c)
#pragma unroll
    for (int e = 0; e < 4; ++e) dot += qv[c][e] * kv[c][e];

  float other = __shfl_xor(dot, 32, 64);
  float d0 = (l < 32) ? dot : other;
  float d1 = (l < 32) ? other : dot;
  float score = (w0 * d0 + wx * d1) * 0.17677669529663687f;  // 1/sqrt(32)

  float m1 = fmaxf(score, __shfl_xor(score, 1, 64));
  float mx = fmaxf(m1, __shfl_xor(m1, 2, 64));
  float e0 = expf(score - mx);
  float s1 = e0 + __shfl_xor(e0, 1, 64);
  float ssum = s1 + __shfl_xor(s1, 2, 64);
  float attn = e0 / ssum;
  int edge = (x0 == Mm1);
  float c1v = edge ? 0.0f : attn * wx;
  float c0v = edge ? attn * (w0 + wx) : attn * w0;

  const int oh = l >> 3, os = l & 7;
  float cc0[4], cc1[4];
#pragma unroll
  for (int m = 0; m < 4; ++m) {
    cc0[m] = __shfl(c0v, oh * 4 + m, 64);
    cc1[m] = __shfl(c1v, oh * 4 + m, 64);
  }

  WAIT_VM(0);

  float acc[4] = {};
#pragma unroll
  for (int m = 0; m < 4; ++m) {
    int pt = oh * 4 + m;
    int pos0 = (os >> 1) ^ (pt & 7);
    int pos1 = (4 + (os >> 1)) ^ (pt & 7);
    const char* pb = vbuf + pt * 128 + (os & 1) * 8;
    ushort4 v0 = *(const ushort4*)(pb + pos0 * 16);
    ushort4 v1 = *(const ushort4*)(pb + pos1 * 16);
#pragma unroll
    for (int e = 0; e < 4; ++e)
      acc[e] += cc0[m] * bf2f((&v0.x)[e]) + cc1[m] * bf2f((&v1.x)[e]);
  }
  ushort4 ow;
#pragma unroll
  for (int e = 0; e < 4; ++e) (&ow.x)[e] = f2bf(acc[e]);
  *(ushort4*)(out2 + (size_t)n * 256 + oh * 32 + os * 4) = ow;
}

// ---------------------------------------------------------------------------
// Fused dispatches (overlap independent work within one grid):
// K1: blocks 0..511 = fa value-GEMM; 512..1023 = loc GEMM.  (both co-resident)
__global__ __launch_bounds__(256) void k_fa_loc(
    const float* __restrict__ value, const ushort* __restrict__ WvT,
    const float* __restrict__ bv, ushort* __restrict__ vtabT,
    const float* __restrict__ query, const float* __restrict__ Wr,
    const float* __restrict__ Wo, float* __restrict__ locr) {
  __shared__ __align__(16) char smem[34048];
  int b = blockIdx.x;
  if (b < 512) fa_body(value, WvT, bv, vtabT, smem, b);
  else         loc_body(query, Wr, Wo, locr, smem, b - 512);
}

// K2: attn on first half of queries.
__global__ __launch_bounds__(256) void k_attn0(
    const float* __restrict__ query, const float* __restrict__ key,
    const ushort* __restrict__ vtabT, const float* __restrict__ locr,
    const float* __restrict__ br, const float* __restrict__ bo,
    ushort* __restrict__ out2) {
  __shared__ __align__(16) char smem[16384];
  attn_body(query, key, vtabT, locr, br, bo, out2, smem, blockIdx.x, 0);
}

// K3: out-GEMM(half0) [blocks 0..255, MFMA-bound] overlapped with
//     attn(half1)     [blocks 256.., L3-gather-bound].
__global__ __launch_bounds__(256) void k_mid(
    const ushort* __restrict__ out2, const ushort* __restrict__ WoT,
    const float* __restrict__ bout, float* __restrict__ out,
    const float* __restrict__ query, const float* __restrict__ key,
    const ushort* __restrict__ vtabT, const float* __restrict__ locr,
    const float* __restrict__ br, const float* __restrict__ bo,
    ushort* __restrict__ out2w) {
  __shared__ __align__(16) char smem[16384];
  int b = blockIdx.x;
  if (b < 256) gemm_body(out2, WoT, bout, out, smem, b, 0);
  else attn_body(query, key, vtabT, locr, br, bo, out2w, smem, b - 256, NHALF);
}

// K4: out-GEMM on second half.
__global__ __launch_bounds__(256) void k_out1(
    const ushort* __restrict__ out2, const ushort* __restrict__ WoT,
    const float* __restrict__ bout, float* __restrict__ out) {
  __shared__ __align__(16) char smem[16384];
  gemm_body(out2, WoT, bout, out, smem, blockIdx.x, NHALF);
}

// ---------------------------------------------------------------------------
extern "C" void kernel_launch(void* const* d_in, const int* in_sizes, int n_in,
                              void* d_out, int out_size, void* d_ws, size_t ws_size,
                              hipStream_t stream) {
  const float* query = (const float*)d_in[0];
  const float* key   = (const float*)d_in[1];
  const float* value = (const float*)d_in[2];
  const float* Wr    = (const float*)d_in[3];
  const float* br    = (const float*)d_in[4];
  const float* Wo    = (const float*)d_in[5];
  const float* bo    = (const float*)d_in[6];
  const float* Wv    = (const float*)d_in[7];
  const float* bv    = (const float*)d_in[8];
  const float* Wout  = (const float*)d_in[9];
  const float* bout  = (const float*)d_in[10];
  float* out = (float*)d_out;

  char* ws = (char*)d_ws;
  ushort* out2  = (ushort*)(ws);                         // 16 MB
  ushort* vtabT = (ushort*)(ws + (16u << 20));           // 16 MB [H][M][Ch]
  float*  locr  = (float*) (ws + (32u << 20));           //  8 MB
  ushort* WvT   = (ushort*)(ws + (40u << 20));           // 128 KB
  ushort* WoT   = (ushort*)(ws + (40u << 20) + (1u << 17));

  // K0: both weight transposes
  transpose_both<<<512, 256, 0, stream>>>(Wv, Wout, WvT, WoT);
  // K1: value GEMM (-> vtabT) overlapped with loc GEMM (-> locr)
  k_fa_loc<<<1024, 256, 0, stream>>>(value, WvT, bv, vtabT,
                                     query, Wr, Wo, locr);
  // K2: attn on rows [0, NQ/2)
  k_attn0<<<NHALF / 4, 256, 0, stream>>>(query, key, vtabT, locr, br, bo, out2);
  // K3: out-GEMM on rows [0, NQ/2) overlapped with attn on [NQ/2, NQ)
  k_mid<<<256 + NHALF / 4, 256, 0, stream>>>(out2, WoT, bout, out,
                                             query, key, vtabT, locr, br, bo,
                                             out2);
  // K4: out-GEMM on rows [NQ/2, NQ)
  k_out1<<<256, 256, 0, stream>>>(out2, WoT, bout, out);
}

// Round 12
// 106.195 us; speedup vs baseline: 1.0295x; 1.0295x over previous
//
#include <hip/hip_runtime.h>
#include <hip/hip_bf16.h>
#include <stdint.h>

// Problem constants (fixed by the reference)
#define NQ    32768
#define NKV   32768
#define CDIM  256
#define NHEADS 8
#define NPTS  4

using bf16x8 = __attribute__((ext_vector_type(8))) short;
using f32x4  = __attribute__((ext_vector_type(4))) float;
using u16x8  = __attribute__((ext_vector_type(8))) ushort;

static __device__ __forceinline__ ushort f2bf(float f) {
  uint32_t u = __float_as_uint(f);
  return (ushort)((u + 0x7FFFu + ((u >> 16) & 1u)) >> 16);  // RNE
}
static __device__ __forceinline__ float bf2f(ushort h) {
  return __uint_as_float(((uint32_t)h) << 16);
}
static __device__ __forceinline__ void async16(const void* g, void* l) {
  __builtin_amdgcn_global_load_lds(
      (const __attribute__((address_space(1))) uint32_t*)g,
      (__attribute__((address_space(3))) uint32_t*)l, 16, 0, 0);
}
#define WAIT_VM(N) do { asm volatile("s_waitcnt vmcnt(" #N ")" ::: "memory"); \
                        __builtin_amdgcn_sched_barrier(0); } while (0)

// ---------------------------------------------------------------------------
// K0: both W transposes in one launch. b<256: Wv -> WvT, else Wout -> WoT.
__global__ __launch_bounds__(256) void transpose_both(
    const float* __restrict__ Wv, const float* __restrict__ Wout,
    ushort* __restrict__ WvT, ushort* __restrict__ WoT) {
  int b = blockIdx.x, k = threadIdx.x;
  if (b < 256) WvT[b * 256 + k] = f2bf(Wv[k * 256 + b]);
  else { int j = b - 256; WoT[j * 256 + k] = f2bf(Wout[k * 256 + j]); }
}

// ---------------------------------------------------------------------------
// K1: value GEMM, nt-MERGED: one block owns 128 rows x ALL 256 cols, so the
// f32 A panel is read ONCE (33.5MB, was 67MB with the nt split). A is
// f32->bf16 converted during staging; C goes out transposed to vtabT[H][M][Ch]
// via a 16KB LDS-transpose epilogue (4 passes x 2 heads, coalesced u16x8).
// grid=256 (1 block/CU). LDS 24KB. acc[4][8] => ~200 VGPR (bounds 256,1).
__global__ __launch_bounds__(256, 1) void gemm_fa256(
    const float* __restrict__ Af, const ushort* __restrict__ BT,
    const float* __restrict__ bias, ushort* __restrict__ CbT) {
  __shared__ __align__(16) ushort S[128 * 32 + 256 * 32];  // 8KB A + 16KB B
  ushort* Alds = S;
  ushort* Blds = S + 128 * 32;
  const int t = threadIdx.x;
  const int wave = t >> 6, lane = t & 63;
  const int m0 = blockIdx.x * 128;
  const int wr = wave >> 1, wc = wave & 1;
  const int r16 = lane & 15, kb = (lane >> 4) * 8;

  f32x4 acc[4][8] = {};

  for (int kt = 0; kt < 256; kt += 32) {
    __syncthreads();
#pragma unroll
    for (int it = 0; it < 4; ++it) {  // B: 256 rows x 32k = 16KB, gload_lds
      int c = it * 256 + t;
      int row = c >> 2, cc = c & 3;
      async16(BT + ((size_t)row * 256 + kt + cc * 8),
              Blds + (size_t)(it * 256 + wave * 64) * 8);
    }
#pragma unroll
    for (int it = 0; it < 2; ++it) {  // A: f32 -> reg -> bf16 -> ds_write
      int c = it * 256 + t;
      int row = c >> 2, cc = c & 3;
      const float* src = Af + (size_t)(m0 + row) * 256 + kt + cc * 8;
      f32x4 a = *(const f32x4*)src;
      f32x4 b = *(const f32x4*)(src + 4);
      u16x8 w;
#pragma unroll
      for (int e = 0; e < 4; ++e) { w[e] = f2bf(a[e]); w[4 + e] = f2bf(b[e]); }
      *(u16x8*)&Alds[(size_t)c * 8] = w;
    }
    __syncthreads();  // covers vmcnt (B) + lgkm (A ds_write)

    bf16x8 af[4], bfr[8];
#pragma unroll
    for (int m = 0; m < 4; ++m)
      af[m] = *(const bf16x8*)&Alds[(wr * 64 + m * 16 + r16) * 32 + kb];
#pragma unroll
    for (int n = 0; n < 8; ++n)
      bfr[n] = *(const bf16x8*)&Blds[(wc * 128 + n * 16 + r16) * 32 + kb];
#pragma unroll
    for (int m = 0; m < 4; ++m)
#pragma unroll
      for (int n = 0; n < 8; ++n)
        acc[m][n] = __builtin_amdgcn_mfma_f32_16x16x32_bf16(af[m], bfr[n],
                                                            acc[m][n], 0, 0, 0);
  }

  // epilogue: 4 passes x 2 heads through a 16KB LDS transpose
  const int rg = lane >> 4;
#pragma unroll
  for (int p = 0; p < 4; ++p) {
    __syncthreads();                     // prev pass copies / K-loop reads done
    if (wc == (p >> 1)) {
      int nbase = (p & 1) * 4;
#pragma unroll
      for (int m = 0; m < 4; ++m)
#pragma unroll
        for (int nn = 0; nn < 4; ++nn) {
          int n = nbase + nn;
          int gc = wc * 128 + n * 16 + r16;  // global col
          int colp = gc - p * 64;            // 0..63 within this pass
          int hh = colp >> 5, ch = colp & 31;
          float bb = bias[gc];
#pragma unroll
          for (int r = 0; r < 4; ++r) {
            int row = wr * 64 + m * 16 + rg * 4 + r;
            S[(hh * 128 + row) * 32 + ch] = f2bf(acc[m][n][r] + bb);
          }
        }
    }
    __syncthreads();
#pragma unroll
    for (int i = 0; i < 4; ++i) {        // copy out 16KB, coalesced u16x8
      int chunk = i * 256 + t;
      int hh = chunk >> 9, within = chunk & 511;
      u16x8 w = *(const u16x8*)&S[chunk * 8];
      ushort* dst = CbT + ((size_t)(p * 2 + hh) * NKV + m0) * 32;
      *(u16x8*)(dst + within * 8) = w;
    }
  }
}

// ---------------------------------------------------------------------------
// K4: out GEMM, nt-MERGED: 128 rows x all 256 cols per block; out2 read once
// (16MB, was 32). A bf16 via gload_lds; C written f32 directly.
__global__ __launch_bounds__(256, 1) void gemm_out256(
    const ushort* __restrict__ A, const ushort* __restrict__ BT,
    const float* __restrict__ bias, float* __restrict__ Cf) {
  __shared__ __align__(16) ushort S[128 * 32 + 256 * 32];
  ushort* Alds = S;
  ushort* Blds = S + 128 * 32;
  const int t = threadIdx.x;
  const int wave = t >> 6, lane = t & 63;
  const int m0 = blockIdx.x * 128;
  const int wr = wave >> 1, wc = wave & 1;
  const int r16 = lane & 15, kb = (lane >> 4) * 8;

  f32x4 acc[4][8] = {};

  for (int kt = 0; kt < 256; kt += 32) {
    __syncthreads();
#pragma unroll
    for (int it = 0; it < 4; ++it) {  // B: 16KB
      int c = it * 256 + t;
      int row = c >> 2, cc = c & 3;
      async16(BT + ((size_t)row * 256 + kt + cc * 8),
              Blds + (size_t)(it * 256 + wave * 64) * 8);
    }
#pragma unroll
    for (int it = 0; it < 2; ++it) {  // A: 8KB
      int c = it * 256 + t;
      int row = c >> 2, cc = c & 3;
      async16(A + ((size_t)(m0 + row) * 256 + kt + cc * 8),
              Alds + (size_t)(it * 256 + wave * 64) * 8);
    }
    __syncthreads();

    bf16x8 af[4], bfr[8];
#pragma unroll
    for (int m = 0; m < 4; ++m)
      af[m] = *(const bf16x8*)&Alds[(wr * 64 + m * 16 + r16) * 32 + kb];
#pragma unroll
    for (int n = 0; n < 8; ++n)
      bfr[n] = *(const bf16x8*)&Blds[(wc * 128 + n * 16 + r16) * 32 + kb];
#pragma unroll
    for (int m = 0; m < 4; ++m)
#pragma unroll
      for (int n = 0; n < 8; ++n)
        acc[m][n] = __builtin_amdgcn_mfma_f32_16x16x32_bf16(af[m], bfr[n],
                                                            acc[m][n], 0, 0, 0);
  }

  const int rg = lane >> 4;
#pragma unroll
  for (int m = 0; m < 4; ++m)
#pragma unroll
    for (int n = 0; n < 8; ++n) {
      int gc = wc * 128 + n * 16 + r16;
      float bb = bias[gc];
#pragma unroll
      for (int r = 0; r < 4; ++r) {
        int gr = m0 + wr * 64 + m * 16 + rg * 4 + r;
        Cf[(size_t)gr * 256 + gc] = acc[m][n][r] + bb;
      }
    }
}

// ---------------------------------------------------------------------------
// K2: loc_raw[N,64] = query @ [Wr_even | Wo_even]   (fp32 score path —
// bf16 here would shift sampling indices by ~100s and blow the threshold).
__global__ __launch_bounds__(256) void loc_gemm(const float* __restrict__ Q,
                                                const float* __restrict__ Wr,
                                                const float* __restrict__ Wo,
                                                float* __restrict__ locr) {
  __shared__ float AT[64][68];
  __shared__ float Bl[64][64];
  const int m0 = blockIdx.x * 64;
  const int t = threadIdx.x;
  const int tr = t >> 4, tc = t & 15;
  float acc[4][4] = {};

  for (int k0 = 0; k0 < 256; k0 += 64) {
    __syncthreads();
#pragma unroll
    for (int i = 0; i < 4; ++i) {
      int row = (t >> 4) + 16 * i;
      int kk = (t & 15) * 4;
      float4 v = *(const float4*)&Q[(size_t)(m0 + row) * 256 + k0 + kk];
      AT[kk + 0][row] = v.x; AT[kk + 1][row] = v.y;
      AT[kk + 2][row] = v.z; AT[kk + 3][row] = v.w;
    }
#pragma unroll
    for (int i = 0; i < 16; ++i) {
      int j = t & 63;
      int kk = (t >> 6) + 4 * i;
      float v = (j < 32) ? Wr[(size_t)(k0 + kk) * 64 + 2 * j]
                         : Wo[(size_t)(k0 + kk) * 64 + 2 * (j - 32)];
      Bl[kk][j] = v;
    }
    __syncthreads();
#pragma unroll 8
    for (int kk = 0; kk < 64; ++kk) {
      float4 a = *(const float4*)&AT[kk][tr * 4];
      float4 b = *(const float4*)&Bl[kk][tc * 4];
      float av[4] = {a.x, a.y, a.z, a.w};
      float bv4[4] = {b.x, b.y, b.z, b.w};
#pragma unroll
      for (int i = 0; i < 4; ++i)
#pragma unroll
        for (int jj = 0; jj < 4; ++jj) acc[i][jj] += av[i] * bv4[jj];
    }
  }
#pragma unroll
  for (int i = 0; i < 4; ++i)
#pragma unroll
    for (int jj = 0; jj < 4; ++jj)
      locr[(size_t)(m0 + tr * 4 + i) * 64 + tc * 4 + jj] = acc[i][jj];
}

// ---------------------------------------------------------------------------
// K3: fused sampling + attention (r8 structure — measured structural floor
// across 6 designs: the random 128B-line gather stream through L2/L3 pins
// this at ~50µs regardless of staging style / occupancy / cache hints).
// Wave = 1 query row; v pairs staged to LDS (4KB/wave from vtabT), k/q
// per-lane register loads (lane<32: x0 row, lane>=32: x1 row).
//  v pair pt (128B = rows x0,x0+1 of head pt>>2): pos p holds chunk p^(pt&7)
__global__ __launch_bounds__(256, 4) void sample_attn(
    const float* __restrict__ query, const float* __restrict__ key,
    const ushort* __restrict__ vtabT, const float* __restrict__ locr,
    const float* __restrict__ br, const float* __restrict__ bo,
    ushort* __restrict__ out2) {
  __shared__ char smem[4][4096];
  const int wave = threadIdx.x >> 6, l = threadIdx.x & 63;
  const int j = l & 31;
  const int n = blockIdx.x * 4 + wave;
  const int Mm1 = NKV - 1;
  char* vbuf = smem[wave];

  float rr = locr[(size_t)n * 64 + j];
  float oo = locr[(size_t)n * 64 + 32 + j];
  float ref = 1.0f / (1.0f + expf(-(rr + br[2 * j])));
  float x = (ref + (oo + bo[2 * j])) * (float)Mm1;
  float xf = floorf(x);
  int x0 = (int)fminf(fmaxf(xf, 0.0f), (float)Mm1);
  int x1 = (x0 + 1 > Mm1) ? Mm1 : x0 + 1;
  float wx = x - (float)x0;
  float w0 = 1.0f - wx;

  // stage v pairs FIRST (latency hides under score phase)
  {
    const int pg3 = l >> 3, c7 = l & 7;
    const int sc = c7 ^ pg3;
#pragma unroll
    for (int i = 0; i < 4; ++i) {
      int pg = i * 8 + pg3;
      int row = __shfl(x0, pg, 64);
      async16(vtabT + ((size_t)(pg >> 2) * NKV + row) * 32 + sc * 8,
              vbuf + i * 1024);
    }
  }
  __builtin_amdgcn_sched_barrier(0);

  // k + q per-lane register loads (lane-local rows, no shuffles)
  const int myrow = (l < 32) ? x0 : x1;
  const float* kr = key + (size_t)myrow * 256 + (j >> 2) * 32;
  const float* qr = query + (size_t)n * 256 + (j >> 2) * 32;
  f32x4 kv[8], qv[8];
#pragma unroll
  for (int c = 0; c < 8; ++c) kv[c] = *(const f32x4*)(kr + c * 4);
#pragma unroll
  for (int c = 0; c < 8; ++c) qv[c] = *(const f32x4*)(qr + c * 4);
  __builtin_amdgcn_sched_barrier(0);

  float dot = 0.f;
#pragma unroll
  for (int c = 0; c < 8; ++c)
#pragma unroll
    for (int e = 0; e < 4; ++e) dot += qv[c][e] * kv[c][e];

  float other = __shfl_xor(dot, 32, 64);
  float d0 = (l < 32) ? dot : other;
  float d1 = (l < 32) ? other : dot;
  float score = (w0 * d0 + wx * d1) * 0.17677669529663687f;  // 1/sqrt(32)

  float m1 = fmaxf(score, __shfl_xor(score, 1, 64));
  float mx = fmaxf(m1, __shfl_xor(m1, 2, 64));
  float e0 = expf(score - mx);
  float s1 = e0 + __shfl_xor(e0, 1, 64);
  float ssum = s1 + __shfl_xor(s1, 2, 64);
  float attn = e0 / ssum;
  // v-pair holds rows [x0, x0+1]; at x0==M-1 the 2nd half is garbage but the
  // reference value is v[x0] exactly (g0==g1): fold w0+wx=1 into c0.
  int edge = (x0 == Mm1);
  float c1v = edge ? 0.0f : attn * wx;
  float c0v = edge ? attn * (w0 + wx) : attn * w0;

  const int oh = l >> 3, os = l & 7;
  float cc0[4], cc1[4];
#pragma unroll
  for (int m = 0; m < 4; ++m) {
    cc0[m] = __shfl(c0v, oh * 4 + m, 64);
    cc1[m] = __shfl(c1v, oh * 4 + m, 64);
  }

  WAIT_VM(0);

  float acc[4] = {};
#pragma unroll
  for (int m = 0; m < 4; ++m) {
    int pt = oh * 4 + m;
    int pos0 = (os >> 1) ^ (pt & 7);
    int pos1 = (4 + (os >> 1)) ^ (pt & 7);
    const char* pb = vbuf + pt * 128 + (os & 1) * 8;
    ushort4 v0 = *(const ushort4*)(pb + pos0 * 16);
    ushort4 v1 = *(const ushort4*)(pb + pos1 * 16);
#pragma unroll
    for (int e = 0; e < 4; ++e)
      acc[e] += cc0[m] * bf2f((&v0.x)[e]) + cc1[m] * bf2f((&v1.x)[e]);
  }
  ushort4 ow;
#pragma unroll
  for (int e = 0; e < 4; ++e) (&ow.x)[e] = f2bf(acc[e]);
  *(ushort4*)(out2 + (size_t)n * 256 + oh * 32 + os * 4) = ow;
}

// ---------------------------------------------------------------------------
extern "C" void kernel_launch(void* const* d_in, const int* in_sizes, int n_in,
                              void* d_out, int out_size, void* d_ws, size_t ws_size,
                              hipStream_t stream) {
  const float* query = (const float*)d_in[0];
  const float* key   = (const float*)d_in[1];
  const float* value = (const float*)d_in[2];
  const float* Wr    = (const float*)d_in[3];
  const float* br    = (const float*)d_in[4];
  const float* Wo    = (const float*)d_in[5];
  const float* bo    = (const float*)d_in[6];
  const float* Wv    = (const float*)d_in[7];
  const float* bv    = (const float*)d_in[8];
  const float* Wout  = (const float*)d_in[9];
  const float* bout  = (const float*)d_in[10];
  float* out = (float*)d_out;

  char* ws = (char*)d_ws;
  ushort* out2  = (ushort*)(ws);                         // 16 MB
  ushort* vtabT = (ushort*)(ws + (16u << 20));           // 16 MB [H][M][Ch]
  float*  locr  = (float*) (ws + (32u << 20));           //  8 MB
  ushort* WvT   = (ushort*)(ws + (40u << 20));           // 128 KB
  ushort* WoT   = (ushort*)(ws + (40u << 20) + (1u << 17));

  // K0: both weight transposes
  transpose_both<<<512, 256, 0, stream>>>(Wv, Wout, WvT, WoT);
  // K1: vtabT = bf16(value @ Wv + bv), transposed (A read once, nt-merged)
  gemm_fa256<<<NQ / 128, 256, 0, stream>>>(value, WvT, bv, vtabT);
  // K2: loc_raw = query @ [Wr_even | Wo_even]  (fp32)
  loc_gemm<<<NQ / 64, 256, 0, stream>>>(query, Wr, Wo, locr);
  // K3: fused sampling/attention -> out2 (bf16)
  sample_attn<<<NQ / 4, 256, 0, stream>>>(query, key, vtabT, locr, br, bo, out2);
  // K4: out = out2 @ Wout + bout  (f32, out2 read once, nt-merged)
  gemm_out256<<<NQ / 128, 256, 0, stream>>>(out2, WoT, bout, out);
}

// Round 13
// 97.349 us; speedup vs baseline: 1.1230x; 1.0909x over previous
//
#include <hip/hip_runtime.h>
#include <hip/hip_bf16.h>
#include <stdint.h>

// Problem constants (fixed by the reference)
#define NQ    32768
#define NKV   32768
#define CDIM  256
#define NHEADS 8
#define NPTS  4

using bf16x8 = __attribute__((ext_vector_type(8))) short;
using f32x4  = __attribute__((ext_vector_type(4))) float;
using u16x8  = __attribute__((ext_vector_type(8))) ushort;

static __device__ __forceinline__ ushort f2bf(float f) {
  uint32_t u = __float_as_uint(f);
  return (ushort)((u + 0x7FFFu + ((u >> 16) & 1u)) >> 16);  // RNE
}
static __device__ __forceinline__ float bf2f(ushort h) {
  return __uint_as_float(((uint32_t)h) << 16);
}
static __device__ __forceinline__ void async16(const void* g, void* l) {
  __builtin_amdgcn_global_load_lds(
      (const __attribute__((address_space(1))) uint32_t*)g,
      (__attribute__((address_space(3))) uint32_t*)l, 16, 0, 0);
}
#define WAIT_VM(N) do { asm volatile("s_waitcnt vmcnt(" #N ")" ::: "memory"); \
                        __builtin_amdgcn_sched_barrier(0); } while (0)

// ---------------------------------------------------------------------------
// K0: both W transposes in one launch. b<256: Wv -> WvT, else Wout -> WoT.
__global__ __launch_bounds__(256) void transpose_both(
    const float* __restrict__ Wv, const float* __restrict__ Wout,
    ushort* __restrict__ WvT, ushort* __restrict__ WoT) {
  int b = blockIdx.x, k = threadIdx.x;
  if (b < 256) WvT[b * 256 + k] = f2bf(Wv[k * 256 + b]);
  else { int j = b - 256; WoT[j * 256 + k] = f2bf(Wout[k * 256 + j]); }
}

// ---------------------------------------------------------------------------
// K4: bf16 MFMA GEMM  C[M,256] = A[M,256] * B + bias   (A bf16, C f32).
// nt-split 128x128 tile, BK=32, 4 waves 2x2, 16KB LDS, 2-3 blocks/CU
// (r12's nt-merged 1-block/CU variant was latency-starved — reverted).
__global__ __launch_bounds__(256) void gemm_mfma(
    const ushort* __restrict__ A, const ushort* __restrict__ BT,
    const float* __restrict__ bias, float* __restrict__ Cf) {
  __shared__ ushort Alds[128 * 32];
  __shared__ ushort Blds[128 * 32];
  const int t = threadIdx.x;
  const int wave = t >> 6, lane = t & 63;
  const int mt = blockIdx.x >> 1, nt = blockIdx.x & 1;
  const int m0 = mt * 128, n0 = nt * 128;
  const int wr = wave >> 1, wc = wave & 1;
  const int r16 = lane & 15, kb = (lane >> 4) * 8;

  f32x4 acc[4][4] = {};

  for (int kt = 0; kt < 256; kt += 32) {
    __syncthreads();
#pragma unroll
    for (int it = 0; it < 2; ++it) {
      int c = it * 256 + t;
      int row = c >> 2, cc = c & 3;
      async16(A  + ((size_t)(m0 + row) * 256 + kt + cc * 8),
              Alds + (size_t)(it * 256 + wave * 64) * 8);
      async16(BT + ((size_t)(n0 + row) * 256 + kt + cc * 8),
              Blds + (size_t)(it * 256 + wave * 64) * 8);
    }
    __syncthreads();

    bf16x8 af[4], bfr[4];
#pragma unroll
    for (int m = 0; m < 4; ++m)
      af[m] = *(const bf16x8*)&Alds[(wr * 64 + m * 16 + r16) * 32 + kb];
#pragma unroll
    for (int n = 0; n < 4; ++n)
      bfr[n] = *(const bf16x8*)&Blds[(wc * 64 + n * 16 + r16) * 32 + kb];
#pragma unroll
    for (int m = 0; m < 4; ++m)
#pragma unroll
      for (int n = 0; n < 4; ++n)
        acc[m][n] = __builtin_amdgcn_mfma_f32_16x16x32_bf16(af[m], bfr[n],
                                                            acc[m][n], 0, 0, 0);
  }

  const int rg = lane >> 4;
#pragma unroll
  for (int m = 0; m < 4; ++m)
#pragma unroll
    for (int n = 0; n < 4; ++n) {
      int gc = n0 + wc * 64 + n * 16 + r16;
      float bb = bias[gc];
#pragma unroll
      for (int r = 0; r < 4; ++r) {
        int gr = m0 + wr * 64 + m * 16 + rg * 4 + r;
        Cf[(size_t)gr * 256 + gc] = acc[m][n][r] + bb;
      }
    }
}

// K1: value GEMM. A is f32 (converted to bf16 in-register during staging —
// fuses the old convert_val pass) and C is written TRANSPOSED to
// vtabT[H][M][Ch] so sample_attn's (x0,x0+1) value pair is one contiguous
// 128B region. (Scattered-store epilogue — measured equal/better than the
// LDS-transpose epilogue variant, r7 vs r10.)
__global__ __launch_bounds__(256) void gemm_mfma_fa(
    const float* __restrict__ Af, const ushort* __restrict__ BT,
    const float* __restrict__ bias, ushort* __restrict__ CbT) {
  __shared__ ushort Alds[128 * 32];
  __shared__ ushort Blds[128 * 32];
  const int t = threadIdx.x;
  const int wave = t >> 6, lane = t & 63;
  const int mt = blockIdx.x >> 1, nt = blockIdx.x & 1;
  const int m0 = mt * 128, n0 = nt * 128;
  const int wr = wave >> 1, wc = wave & 1;
  const int r16 = lane & 15, kb = (lane >> 4) * 8;

  f32x4 acc[4][4] = {};

  for (int kt = 0; kt < 256; kt += 32) {
    __syncthreads();
#pragma unroll
    for (int it = 0; it < 2; ++it) {  // B via global_load_lds (bf16 already)
      int c = it * 256 + t;
      int row = c >> 2, cc = c & 3;
      async16(BT + ((size_t)(n0 + row) * 256 + kt + cc * 8),
              Blds + (size_t)(it * 256 + wave * 64) * 8);
    }
#pragma unroll
    for (int it = 0; it < 2; ++it) {  // A: f32 -> reg -> bf16 -> ds_write
      int c = it * 256 + t;
      int row = c >> 2, cc = c & 3;
      const float* src = Af + (size_t)(m0 + row) * 256 + kt + cc * 8;
      f32x4 a = *(const f32x4*)src;
      f32x4 b = *(const f32x4*)(src + 4);
      u16x8 w;
#pragma unroll
      for (int e = 0; e < 4; ++e) { w[e] = f2bf(a[e]); w[4 + e] = f2bf(b[e]); }
      *(u16x8*)&Alds[(size_t)c * 8] = w;   // c*8 == row*32 + cc*8
    }
    __syncthreads();  // covers vmcnt (B) + lgkm (A ds_write)

    bf16x8 af[4], bfr[4];
#pragma unroll
    for (int m = 0; m < 4; ++m)
      af[m] = *(const bf16x8*)&Alds[(wr * 64 + m * 16 + r16) * 32 + kb];
#pragma unroll
    for (int n = 0; n < 4; ++n)
      bfr[n] = *(const bf16x8*)&Blds[(wc * 64 + n * 16 + r16) * 32 + kb];
#pragma unroll
    for (int m = 0; m < 4; ++m)
#pragma unroll
      for (int n = 0; n < 4; ++n)
        acc[m][n] = __builtin_amdgcn_mfma_f32_16x16x32_bf16(af[m], bfr[n],
                                                            acc[m][n], 0, 0, 0);
  }

  const int rg = lane >> 4;
#pragma unroll
  for (int m = 0; m < 4; ++m)
#pragma unroll
    for (int n = 0; n < 4; ++n) {
      int gc = n0 + wc * 64 + n * 16 + r16;   // h = gc>>5, ch = gc&31
      float bb = bias[gc];
#pragma unroll
      for (int r = 0; r < 4; ++r) {
        int gr = m0 + wr * 64 + m * 16 + rg * 4 + r;
        CbT[((size_t)(gc >> 5) * NKV + gr) * 32 + (gc & 31)] =
            f2bf(acc[m][n][r] + bb);
      }
    }
}

// ---------------------------------------------------------------------------
// K2: loc_raw[N,64] = query @ [Wr_even | Wo_even]   (fp32 — the score path
// must be fp32-exact: a bf16-level error in loc shifts sampling indices and
// flips clamp regimes, blowing the threshold).
__global__ __launch_bounds__(256) void loc_gemm(const float* __restrict__ Q,
                                                const float* __restrict__ Wr,
                                                const float* __restrict__ Wo,
                                                float* __restrict__ locr) {
  __shared__ float AT[64][68];
  __shared__ float Bl[64][64];
  const int m0 = blockIdx.x * 64;
  const int t = threadIdx.x;
  const int tr = t >> 4, tc = t & 15;
  float acc[4][4] = {};

  for (int k0 = 0; k0 < 256; k0 += 64) {
    __syncthreads();
#pragma unroll
    for (int i = 0; i < 4; ++i) {
      int row = (t >> 4) + 16 * i;
      int kk = (t & 15) * 4;
      float4 v = *(const float4*)&Q[(size_t)(m0 + row) * 256 + k0 + kk];
      AT[kk + 0][row] = v.x; AT[kk + 1][row] = v.y;
      AT[kk + 2][row] = v.z; AT[kk + 3][row] = v.w;
    }
#pragma unroll
    for (int i = 0; i < 16; ++i) {
      int j = t & 63;
      int kk = (t >> 6) + 4 * i;
      float v = (j < 32) ? Wr[(size_t)(k0 + kk) * 64 + 2 * j]
                         : Wo[(size_t)(k0 + kk) * 64 + 2 * (j - 32)];
      Bl[kk][j] = v;
    }
    __syncthreads();
#pragma unroll 8
    for (int kk = 0; kk < 64; ++kk) {
      float4 a = *(const float4*)&AT[kk][tr * 4];
      float4 b = *(const float4*)&Bl[kk][tc * 4];
      float av[4] = {a.x, a.y, a.z, a.w};
      float bv4[4] = {b.x, b.y, b.z, b.w};
#pragma unroll
      for (int i = 0; i < 4; ++i)
#pragma unroll
        for (int jj = 0; jj < 4; ++jj) acc[i][jj] += av[i] * bv4[jj];
    }
  }
#pragma unroll
  for (int i = 0; i < 4; ++i)
#pragma unroll
    for (int jj = 0; jj < 4; ++jj)
      locr[(size_t)(m0 + tr * 4 + i) * 64 + tc * 4 + jj] = acc[i][jj];
}

// ---------------------------------------------------------------------------
// K3: fused sampling + attention — round-7 variant (best measured: ~48µs).
// Wave = 1 query row; q per-lane regs (quad lanes share addrs -> L1 bcast);
// k slices staged to LDS (8KB/wave, 1 TA-lookup per 128B line); v pairs
// staged to LDS (4KB/wave from vtabT so x0/x0+1 are one contiguous 128B).
// Single memory round-trip: all 12 global_load_lds issue back-to-back;
// score waits vmcnt(4), v-combine waits vmcnt(0). Swizzles on the GLOBAL
// source (LDS dest stays linear), bank-balanced per 8-lane service group:
//  k slot s (s<32: k0 of pt=s; else k1): pos p holds chunk p^(s&7)^((s>>3)&3)
//  v pair pt (128B = rows x0,x0+1 of head pt>>2): pos p holds chunk p^(pt&7)
// This kernel is at its structural floor (~50µs): six designs spanning
// reg/LDS staging, occupancy 27-61%, request elision, and L1 bypass all
// land 48-55µs — the random-128B-line stream through L2-miss/L3 is the wall.
__global__ __launch_bounds__(256) void sample_attn(
    const float* __restrict__ query, const float* __restrict__ key,
    const ushort* __restrict__ vtabT, const float* __restrict__ locr,
    const float* __restrict__ br, const float* __restrict__ bo,
    ushort* __restrict__ out2) {
  __shared__ char smem[4][12288];           // 8KB k + 4KB v per wave
  const int wave = threadIdx.x >> 6, l = threadIdx.x & 63;
  const int j = l & 31;                     // point id (dup in both halves)
  const int n = blockIdx.x * 4 + wave;
  const int Mm1 = NKV - 1;
  char* kbuf = smem[wave];
  char* vbuf = kbuf + 8192;

  // sampling location for point j
  float rr = locr[(size_t)n * 64 + j];
  float oo = locr[(size_t)n * 64 + 32 + j];
  float ref = 1.0f / (1.0f + expf(-(rr + br[2 * j])));
  float x = (ref + (oo + bo[2 * j])) * (float)Mm1;
  float xf = floorf(x);
  int x0 = (int)fminf(fmaxf(xf, 0.0f), (float)Mm1);
  int x1 = (x0 + 1 > Mm1) ? Mm1 : x0 + 1;
  float wx = x - (float)x0;
  float w0 = 1.0f - wx;

  // ---- q per-lane (issued first; quad lanes share addresses -> L1 bcast)
  const float* qr = query + (size_t)n * 256 + (j >> 2) * 32;
  f32x4 qv[8];
#pragma unroll
  for (int c = 0; c < 8; ++c) qv[c] = *(const f32x4*)(qr + c * 4);
  __builtin_amdgcn_sched_barrier(0);

  // ---- stage k: 8 instrs; instr i covers slots i*8..i*8+7
  {
    const int ptg = l >> 3, p7 = l & 7;
#pragma unroll
    for (int i = 0; i < 8; ++i) {
      int pt = ((i & 3) << 3) + ptg;
      int row = (i < 4) ? __shfl(x0, pt, 64) : __shfl(x1, pt, 64);
      int sc = p7 ^ ptg ^ (i & 3);
      async16(key + (size_t)row * 256 + (pt >> 2) * 32 + (sc << 2),
              kbuf + i * 1024);
    }
  }
  __builtin_amdgcn_sched_barrier(0);
  // ---- stage v pairs: 4 instrs; instr i covers pairs i*8..i*8+7
  {
    const int pg3 = l >> 3, c7 = l & 7;
    const int sc = c7 ^ pg3;               // pg&7 == pg3
#pragma unroll
    for (int i = 0; i < 4; ++i) {
      int pg = i * 8 + pg3;
      int row = __shfl(x0, pg, 64);
      async16(vtabT + ((size_t)(pg >> 2) * NKV + row) * 32 + sc * 8,
              vbuf + i * 1024);
    }
  }
  __builtin_amdgcn_sched_barrier(0);

  WAIT_VM(4);  // q + k landed (4 v loads still in flight)

  // ---- score: lane l = (which=l>>5, pt=l&31) computes q . k_which[pt]
  float dot = 0.f;
#pragma unroll
  for (int c = 0; c < 8; ++c) {
    int pos = c ^ (l & 7) ^ ((l >> 3) & 3);
    f32x4 kc = *(const f32x4*)(kbuf + l * 128 + pos * 16);
#pragma unroll
    for (int e = 0; e < 4; ++e) dot += qv[c][e] * kc[e];
  }
  float other = __shfl_xor(dot, 32, 64);
  float d0 = (l < 32) ? dot : other;
  float d1 = (l < 32) ? other : dot;
  float score = (w0 * d0 + wx * d1) * 0.17677669529663687f;  // 1/sqrt(32)

  // softmax over the head's 4 points (quad lanes; same in both halves)
  float m1 = fmaxf(score, __shfl_xor(score, 1, 64));
  float mx = fmaxf(m1, __shfl_xor(m1, 2, 64));
  float e0 = expf(score - mx);
  float s1 = e0 + __shfl_xor(e0, 1, 64);
  float ssum = s1 + __shfl_xor(s1, 2, 64);
  float attn = e0 / ssum;
  // v-pair block holds rows [x0, x0+1]; when x0==M-1 its 2nd half is garbage
  // but the reference value is v[x0] exactly (g0==g1): fold w0+wx=1 into c0.
  int edge = (x0 == Mm1);
  float c1v = edge ? 0.0f : attn * wx;
  float c0v = edge ? attn * (w0 + wx) : attn * w0;

  // ---- output: lane (oh=l>>3, os=l&7) owns channels [os*4, os*4+4) of oh
  const int oh = l >> 3, os = l & 7;
  float cc0[4], cc1[4];
#pragma unroll
  for (int m = 0; m < 4; ++m) {
    cc0[m] = __shfl(c0v, oh * 4 + m, 64);
    cc1[m] = __shfl(c1v, oh * 4 + m, 64);
  }

  WAIT_VM(0);  // v landed

  float acc[4] = {};
#pragma unroll
  for (int m = 0; m < 4; ++m) {
    int pt = oh * 4 + m;
    int pos0 = (os >> 1) ^ (pt & 7);        // row x0, chunk os>>1
    int pos1 = (4 + (os >> 1)) ^ (pt & 7);  // row x0+1
    const char* pb = vbuf + pt * 128 + (os & 1) * 8;
    ushort4 v0 = *(const ushort4*)(pb + pos0 * 16);
    ushort4 v1 = *(const ushort4*)(pb + pos1 * 16);
#pragma unroll
    for (int e = 0; e < 4; ++e)
      acc[e] += cc0[m] * bf2f((&v0.x)[e]) + cc1[m] * bf2f((&v1.x)[e]);
  }
  ushort4 ow;
#pragma unroll
  for (int e = 0; e < 4; ++e) (&ow.x)[e] = f2bf(acc[e]);
  *(ushort4*)(out2 + (size_t)n * 256 + oh * 32 + os * 4) = ow;
}

// ---------------------------------------------------------------------------
extern "C" void kernel_launch(void* const* d_in, const int* in_sizes, int n_in,
                              void* d_out, int out_size, void* d_ws, size_t ws_size,
                              hipStream_t stream) {
  const float* query = (const float*)d_in[0];
  const float* key   = (const float*)d_in[1];
  const float* value = (const float*)d_in[2];
  const float* Wr    = (const float*)d_in[3];
  const float* br    = (const float*)d_in[4];
  const float* Wo    = (const float*)d_in[5];
  const float* bo    = (const float*)d_in[6];
  const float* Wv    = (const float*)d_in[7];
  const float* bv    = (const float*)d_in[8];
  const float* Wout  = (const float*)d_in[9];
  const float* bout  = (const float*)d_in[10];
  float* out = (float*)d_out;

  char* ws = (char*)d_ws;
  ushort* out2  = (ushort*)(ws);                         // 16 MB
  ushort* vtabT = (ushort*)(ws + (16u << 20));           // 16 MB [H][M][Ch]
  float*  locr  = (float*) (ws + (32u << 20));           //  8 MB
  ushort* WvT   = (ushort*)(ws + (40u << 20));           // 128 KB
  ushort* WoT   = (ushort*)(ws + (40u << 20) + (1u << 17));

  // K0: both weight transposes (one launch)
  transpose_both<<<512, 256, 0, stream>>>(Wv, Wout, WvT, WoT);
  // K1: vtabT[h][m][ch] = bf16(value @ Wv + bv)  (A f32->bf16 during staging)
  gemm_mfma_fa<<<(NQ / 128) * 2, 256, 0, stream>>>(value, WvT, bv, vtabT);
  // K2: loc_raw = query @ [Wr_even | Wo_even]  (fp32)
  loc_gemm<<<NQ / 64, 256, 0, stream>>>(query, Wr, Wo, locr);
  // K3: fused sampling/attention -> out2 (bf16)
  sample_attn<<<NQ / 4, 256, 0, stream>>>(query, key, vtabT, locr, br, bo, out2);
  // K4: out = out2 @ Wout + bout  (f32)
  gemm_mfma<<<(NQ / 128) * 2, 256, 0, stream>>>(out2, WoT, bout, out);
}